// Round 1
// baseline (78.162 us; speedup 1.0000x reference)
//
#include <hip/hip_runtime.h>

#define NB 8
#define NC 64
#define NN 16384
#define NO 64

// ws layout (floats):
// [0, 1024)    : partial (sum,sumsq) per (b,c)   512*2
// [1024, 1152) : A[64], Bsh[64]
// [1152, 4224) : softmax weights w[b][c][k]      8*64*6

__device__ __forceinline__ void hermite6(float xn, float p[6]) {
    float t = tanhf(xn) * 3.605551275463989f;          // sqrt(13)
    float g = __expf(-0.5f * t * t);
    p[0] = 0.7511255444649425f * g;                    // pi^-1/4
    p[1] = 1.0622519320271969f * t * g;                // sqrt(2)*pi^-1/4
    p[2] = t * p[1] - 0.7071067811865476f * p[0];
    p[3] = 0.816496580927726f * (t * p[2] - p[1]);
    p[4] = 0.7071067811865476f * t * p[3] - 0.8660254037844386f * p[2];
    p[5] = 0.6324555320336759f * t * p[4] - 0.8944271909999159f * p[3];
}

__global__ __launch_bounds__(256) void k_stats(const float* __restrict__ x,
                                               float* __restrict__ part) {
    int bc = blockIdx.x;
    const float* xp = x + (size_t)bc * NN;
    int tid = threadIdx.x;
    float s = 0.f, ss = 0.f;
    #pragma unroll
    for (int i = 0; i < 16; ++i) {
        float4 v = *(const float4*)(xp + i * 1024 + tid * 4);
        s  += v.x + v.y + v.z + v.w;
        ss += v.x * v.x + v.y * v.y + v.z * v.z + v.w * v.w;
    }
    for (int off = 32; off; off >>= 1) {
        s  += __shfl_down(s, off);
        ss += __shfl_down(ss, off);
    }
    __shared__ float red[2][4];
    int lane = tid & 63, wid = tid >> 6;
    if (lane == 0) { red[0][wid] = s; red[1][wid] = ss; }
    __syncthreads();
    if (tid == 0) {
        part[bc * 2 + 0] = red[0][0] + red[0][1] + red[0][2] + red[0][3];
        part[bc * 2 + 1] = red[1][0] + red[1][1] + red[1][2] + red[1][3];
    }
}

__global__ void k_finalize(const float* __restrict__ part,
                           const float* __restrict__ gamma,
                           const float* __restrict__ beta,
                           float* __restrict__ AB) {
    int c = threadIdx.x;  // 64 threads
    float s = 0.f, ss = 0.f;
    for (int b = 0; b < NB; ++b) {
        s  += part[(b * NC + c) * 2 + 0];
        ss += part[(b * NC + c) * 2 + 1];
    }
    const float inv = 1.0f / (float)(NB * NN);
    float mean = s * inv;
    float var  = ss * inv - mean * mean;
    float istd = 1.0f / sqrtf(var + 1e-5f);
    float a = gamma[c] * istd;
    AB[c]      = a;
    AB[64 + c] = beta[c] - mean * a;
}

__global__ __launch_bounds__(256) void k_cost(const float* __restrict__ x,
                                              const float* __restrict__ AB,
                                              float* __restrict__ wout) {
    int bc = blockIdx.x;
    int c  = bc & 63;
    const float* xp = x + (size_t)bc * NN;
    float a = AB[c], bsh = AB[64 + c];
    int tid = threadIdx.x;
    float acc[6] = {0.f, 0.f, 0.f, 0.f, 0.f, 0.f};
    #pragma unroll 4
    for (int i = 0; i < 16; ++i) {
        float4 v = *(const float4*)(xp + i * 1024 + tid * 4);
        float xs[4] = {v.x, v.y, v.z, v.w};
        #pragma unroll
        for (int j = 0; j < 4; ++j) {
            float xn = fmaf(xs[j], a, bsh);
            float p[6];
            hermite6(xn, p);
            #pragma unroll
            for (int k = 0; k < 6; ++k) acc[k] = fmaf(p[k], xn, acc[k]);
        }
    }
    __shared__ float red[6][4];
    int lane = tid & 63, wid = tid >> 6;
    #pragma unroll
    for (int k = 0; k < 6; ++k) {
        float v = acc[k];
        for (int off = 32; off; off >>= 1) v += __shfl_down(v, off);
        if (lane == 0) red[k][wid] = v;
    }
    __syncthreads();
    if (tid == 0) {
        float cst[6];
        float mx = -1e30f;
        #pragma unroll
        for (int k = 0; k < 6; ++k) {
            cst[k] = red[k][0] + red[k][1] + red[k][2] + red[k][3];
            mx = fmaxf(mx, cst[k]);
        }
        float sum = 0.f, e[6];
        #pragma unroll
        for (int k = 0; k < 6; ++k) { e[k] = expf(cst[k] - mx); sum += e[k]; }
        float r = 1.0f / sum;
        #pragma unroll
        for (int k = 0; k < 6; ++k) wout[bc * 6 + k] = e[k] * r;
    }
}

__global__ __launch_bounds__(256) void k_out(const float* __restrict__ x,
                                             const float* __restrict__ Wt,
                                             const float* __restrict__ bias,
                                             const float* __restrict__ AB,
                                             const float* __restrict__ wsm,
                                             float* __restrict__ out) {
    __shared__ float WtT[64 * 64];  // WtT[c*64+o] = Wt[o*64+c]
    __shared__ float wL[64 * 6];
    __shared__ float AL[64], BL[64], biasL[64];
    int tid = threadIdx.x;
    int b    = blockIdx.x >> 5;
    int tile = blockIdx.x & 31;

    for (int i = tid; i < 4096; i += 256) {
        int o = i >> 6, c = i & 63;
        WtT[c * 64 + o] = Wt[i];
    }
    for (int i = tid; i < 384; i += 256) wL[i] = wsm[b * 384 + i];
    if (tid < 64) {
        AL[tid] = AB[tid];
        BL[tid] = AB[64 + tid];
        biasL[tid] = bias[tid];
    }
    __syncthreads();

    int d = tile * 512 + tid * 2;
    const float* xb = x + (size_t)b * NC * NN + d;
    float accA[64], accB[64];
    #pragma unroll
    for (int o = 0; o < 64; ++o) { accA[o] = 0.f; accB[o] = 0.f; }

    float2 xv = *(const float2*)(xb);
    for (int c = 0; c < 64; ++c) {
        float2 nxt = {0.f, 0.f};
        if (c < 63) nxt = *(const float2*)(xb + (size_t)(c + 1) * NN);
        float a = AL[c], bsh = BL[c];
        float w0 = wL[c * 6 + 0], w1 = wL[c * 6 + 1], w2 = wL[c * 6 + 2];
        float w3 = wL[c * 6 + 3], w4 = wL[c * 6 + 4], w5 = wL[c * 6 + 5];

        float p[6];
        float xn0 = fmaf(xv.x, a, bsh);
        hermite6(xn0, p);
        float y0 = w0*p[0] + w1*p[1] + w2*p[2] + w3*p[3] + w4*p[4] + w5*p[5];
        float xn1 = fmaf(xv.y, a, bsh);
        hermite6(xn1, p);
        float y1 = w0*p[0] + w1*p[1] + w2*p[2] + w3*p[3] + w4*p[4] + w5*p[5];

        const float4* wrow = (const float4*)&WtT[c * 64];
        #pragma unroll
        for (int o4 = 0; o4 < 16; ++o4) {
            float4 wv = wrow[o4];
            accA[o4*4+0] = fmaf(wv.x, y0, accA[o4*4+0]);
            accA[o4*4+1] = fmaf(wv.y, y0, accA[o4*4+1]);
            accA[o4*4+2] = fmaf(wv.z, y0, accA[o4*4+2]);
            accA[o4*4+3] = fmaf(wv.w, y0, accA[o4*4+3]);
            accB[o4*4+0] = fmaf(wv.x, y1, accB[o4*4+0]);
            accB[o4*4+1] = fmaf(wv.y, y1, accB[o4*4+1]);
            accB[o4*4+2] = fmaf(wv.z, y1, accB[o4*4+2]);
            accB[o4*4+3] = fmaf(wv.w, y1, accB[o4*4+3]);
        }
        xv = nxt;
    }

    float* ob = out + (size_t)b * NO * NN + d;
    #pragma unroll
    for (int o = 0; o < 64; ++o) {
        float bv = biasL[o];
        float2 st;
        st.x = accA[o] + bv;
        st.y = accB[o] + bv;
        *(float2*)(ob + (size_t)o * NN) = st;
    }
}

extern "C" void kernel_launch(void* const* d_in, const int* in_sizes, int n_in,
                              void* d_out, int out_size, void* d_ws, size_t ws_size,
                              hipStream_t stream) {
    const float* x     = (const float*)d_in[0];
    const float* gamma = (const float*)d_in[1];
    const float* beta  = (const float*)d_in[2];
    const float* Wt    = (const float*)d_in[3];
    const float* bias  = (const float*)d_in[4];
    float* out = (float*)d_out;
    float* ws  = (float*)d_ws;

    float* part = ws;          // 1024
    float* AB   = ws + 1024;   // 128
    float* wsm  = ws + 1152;   // 3072

    k_stats<<<dim3(NB * NC), dim3(256), 0, stream>>>(x, part);
    k_finalize<<<dim3(1), dim3(64), 0, stream>>>(part, gamma, beta, AB);
    k_cost<<<dim3(NB * NC), dim3(256), 0, stream>>>(x, AB, wsm);
    k_out<<<dim3(NB * NC / 2), dim3(256), 0, stream>>>(x, Wt, bias, AB, wsm, out);
}

// Round 2
// 58.089 us; speedup vs baseline: 1.3456x; 1.3456x over previous
//
#include <hip/hip_runtime.h>

#define NB 8
#define NC 64
#define NN 16384
#define NO 64

// ws layout (floats):
// [0, 1024)    : partial (sum,sumsq) per (b,c)   512*2
// [1024, 1152) : A[64], Bsh[64]
// [1152, 4224) : softmax weights w[b][c][k]      8*64*6
// [4224, 8320) : WtT[c*64+o] transposed weights  4096

__device__ __forceinline__ float tanh_fast(float x) {
    // tanh(x) = 1 - 2/(exp(2x)+1); exp->inf and exp->0 limits both correct
    float e = __expf(2.0f * x);
    return 1.0f - 2.0f * __builtin_amdgcn_rcpf(e + 1.0f);
}

__device__ __forceinline__ void hermite6(float xn, float p[6]) {
    float t = tanh_fast(xn) * 3.605551275463989f;      // sqrt(13)
    float g = __expf(-0.5f * t * t);
    p[0] = 0.7511255444649425f * g;                    // pi^-1/4
    p[1] = 1.0622519320271969f * t * g;                // sqrt(2)*pi^-1/4
    p[2] = t * p[1] - 0.7071067811865476f * p[0];
    p[3] = 0.816496580927726f * (t * p[2] - p[1]);
    p[4] = 0.7071067811865476f * t * p[3] - 0.8660254037844386f * p[2];
    p[5] = 0.6324555320336759f * t * p[4] - 0.8944271909999159f * p[3];
}

__global__ __launch_bounds__(256) void k_stats(const float* __restrict__ x,
                                               float* __restrict__ part) {
    int bc = blockIdx.x;
    const float* xp = x + (size_t)bc * NN;
    int tid = threadIdx.x;
    float s = 0.f, ss = 0.f;
    #pragma unroll
    for (int i = 0; i < 16; ++i) {
        float4 v = *(const float4*)(xp + i * 1024 + tid * 4);
        s  += v.x + v.y + v.z + v.w;
        ss += v.x * v.x + v.y * v.y + v.z * v.z + v.w * v.w;
    }
    for (int off = 32; off; off >>= 1) {
        s  += __shfl_down(s, off);
        ss += __shfl_down(ss, off);
    }
    __shared__ float red[2][4];
    int lane = tid & 63, wid = tid >> 6;
    if (lane == 0) { red[0][wid] = s; red[1][wid] = ss; }
    __syncthreads();
    if (tid == 0) {
        part[bc * 2 + 0] = red[0][0] + red[0][1] + red[0][2] + red[0][3];
        part[bc * 2 + 1] = red[1][0] + red[1][1] + red[1][2] + red[1][3];
    }
}

__global__ void k_finalize(const float* __restrict__ part,
                           const float* __restrict__ gamma,
                           const float* __restrict__ beta,
                           const float* __restrict__ Wt,
                           float* __restrict__ AB,
                           float* __restrict__ WtT) {
    int c = threadIdx.x;  // 64 threads
    float s = 0.f, ss = 0.f;
    for (int b = 0; b < NB; ++b) {
        s  += part[(b * NC + c) * 2 + 0];
        ss += part[(b * NC + c) * 2 + 1];
    }
    const float inv = 1.0f / (float)(NB * NN);
    float mean = s * inv;
    float var  = ss * inv - mean * mean;
    float istd = 1.0f / sqrtf(var + 1e-5f);
    float a = gamma[c] * istd;
    AB[c]      = a;
    AB[64 + c] = beta[c] - mean * a;
    // transpose Wt (one-time, tiny): WtT[c*64+o] = Wt[o*64+c]
    for (int o = 0; o < 64; ++o) WtT[c * 64 + o] = Wt[o * 64 + c];
}

__global__ __launch_bounds__(256) void k_cost(const float* __restrict__ x,
                                              const float* __restrict__ AB,
                                              float* __restrict__ wout) {
    int bc = blockIdx.x;
    int c  = bc & 63;
    const float* xp = x + (size_t)bc * NN;
    float a = AB[c], bsh = AB[64 + c];
    int tid = threadIdx.x;
    float acc[6] = {0.f, 0.f, 0.f, 0.f, 0.f, 0.f};
    #pragma unroll 4
    for (int i = 0; i < 16; ++i) {
        float4 v = *(const float4*)(xp + i * 1024 + tid * 4);
        float xs[4] = {v.x, v.y, v.z, v.w};
        #pragma unroll
        for (int j = 0; j < 4; ++j) {
            float xn = fmaf(xs[j], a, bsh);
            float p[6];
            hermite6(xn, p);
            #pragma unroll
            for (int k = 0; k < 6; ++k) acc[k] = fmaf(p[k], xn, acc[k]);
        }
    }
    __shared__ float red[6][4];
    int lane = tid & 63, wid = tid >> 6;
    #pragma unroll
    for (int k = 0; k < 6; ++k) {
        float v = acc[k];
        for (int off = 32; off; off >>= 1) v += __shfl_down(v, off);
        if (lane == 0) red[k][wid] = v;
    }
    __syncthreads();
    if (tid == 0) {
        float cst[6];
        float mx = -1e30f;
        #pragma unroll
        for (int k = 0; k < 6; ++k) {
            cst[k] = red[k][0] + red[k][1] + red[k][2] + red[k][3];
            mx = fmaxf(mx, cst[k]);
        }
        float sum = 0.f, e[6];
        #pragma unroll
        for (int k = 0; k < 6; ++k) { e[k] = expf(cst[k] - mx); sum += e[k]; }
        float r = 1.0f / sum;
        #pragma unroll
        for (int k = 0; k < 6; ++k) wout[bc * 6 + k] = e[k] * r;
    }
}

__global__ __launch_bounds__(256) void k_out(const float* __restrict__ x,
                                             const float* __restrict__ WtTg,
                                             const float* __restrict__ bias,
                                             const float* __restrict__ AB,
                                             const float* __restrict__ wsm,
                                             float* __restrict__ out) {
    __shared__ float WtT[64 * 64];  // WtT[c*64+o]
    __shared__ float wL[64 * 6];
    __shared__ float AL[64], BL[64], biasL[64];
    int tid  = threadIdx.x;
    int b    = blockIdx.x >> 6;
    int tile = blockIdx.x & 63;

    // conflict-free staging: coalesced global read, consecutive LDS write
    #pragma unroll
    for (int i = 0; i < 16; ++i) WtT[i * 256 + tid] = WtTg[i * 256 + tid];
    for (int i = tid; i < 384; i += 256) wL[i] = wsm[b * 384 + i];
    if (tid < 64) {
        AL[tid] = AB[tid];
        BL[tid] = AB[64 + tid];
        biasL[tid] = bias[tid];
    }
    __syncthreads();

    int d = tile * 256 + tid;
    const float* xb = x + (size_t)b * NC * NN + d;
    float acc[64];
    #pragma unroll
    for (int o = 0; o < 64; ++o) acc[o] = 0.f;

    float xv = xb[0];
    for (int c = 0; c < 64; ++c) {
        float nxt = 0.f;
        if (c < 63) nxt = xb[(c + 1) * NN];
        float xn = fmaf(xv, AL[c], BL[c]);
        float p[6];
        hermite6(xn, p);
        float y = wL[c*6+0]*p[0] + wL[c*6+1]*p[1] + wL[c*6+2]*p[2]
                + wL[c*6+3]*p[3] + wL[c*6+4]*p[4] + wL[c*6+5]*p[5];

        const float4* wrow = (const float4*)&WtT[c * 64];
        #pragma unroll
        for (int o4 = 0; o4 < 16; ++o4) {
            float4 wv = wrow[o4];
            acc[o4*4+0] = fmaf(wv.x, y, acc[o4*4+0]);
            acc[o4*4+1] = fmaf(wv.y, y, acc[o4*4+1]);
            acc[o4*4+2] = fmaf(wv.z, y, acc[o4*4+2]);
            acc[o4*4+3] = fmaf(wv.w, y, acc[o4*4+3]);
        }
        xv = nxt;
    }

    float* ob = out + (size_t)b * NO * NN + d;
    #pragma unroll
    for (int o = 0; o < 64; ++o) ob[(size_t)o * NN] = acc[o] + biasL[o];
}

extern "C" void kernel_launch(void* const* d_in, const int* in_sizes, int n_in,
                              void* d_out, int out_size, void* d_ws, size_t ws_size,
                              hipStream_t stream) {
    const float* x     = (const float*)d_in[0];
    const float* gamma = (const float*)d_in[1];
    const float* beta  = (const float*)d_in[2];
    const float* Wt    = (const float*)d_in[3];
    const float* bias  = (const float*)d_in[4];
    float* out = (float*)d_out;
    float* ws  = (float*)d_ws;

    float* part = ws;          // 1024
    float* AB   = ws + 1024;   // 128
    float* wsm  = ws + 1152;   // 3072
    float* WtT  = ws + 4224;   // 4096

    k_stats<<<dim3(NB * NC), dim3(256), 0, stream>>>(x, part);
    k_finalize<<<dim3(1), dim3(64), 0, stream>>>(part, gamma, beta, Wt, AB, WtT);
    k_cost<<<dim3(NB * NC), dim3(256), 0, stream>>>(x, AB, wsm);
    k_out<<<dim3(NB * NC), dim3(256), 0, stream>>>(x, WtT, bias, AB, wsm, out);
}